// Round 2
// baseline (1133.287 us; speedup 1.0000x reference)
//
#include <hip/hip_runtime.h>
#include <hip/hip_bf16.h>
#include <cstdint>
#include <cstddef>

#define T_TOK 8192
#define H_DIM 2048
#define I_DIM 1408
#define E_NUM 8
#define BM 128
#define BN 128
#define BK 64
#define ROWS_CAP (2 * T_TOK + E_NUM * BM) /* 17408 */
#define MAX_MT (ROWS_CAP / BM)            /* 136 */

typedef __attribute__((ext_vector_type(8))) short short8;
typedef __attribute__((ext_vector_type(4))) float f32x4;
typedef __attribute__((ext_vector_type(8))) unsigned short ushort8;

static __device__ __forceinline__ unsigned short f2bf(float f) {
  unsigned u = __float_as_uint(f);
  u += 0x7FFFu + ((u >> 16) & 1u);   // round-to-nearest-even
  return (unsigned short)(u >> 16);
}

static __device__ __forceinline__ void gld_lds16(const void* g, void* l) {
  __builtin_amdgcn_global_load_lds(
      (__attribute__((address_space(1))) unsigned int*)g,
      (__attribute__((address_space(3))) unsigned int*)l, 16, 0, 0);
}

// ---------------- router: fp32 logits, softmax, top-2, expert histogram ----
__global__ __launch_bounds__(256) void router_kernel(
    const float* __restrict__ x, const float* __restrict__ rw,
    int* __restrict__ topk_idx, float* __restrict__ topk_w, int* __restrict__ meta) {
  int t = blockIdx.x * 4 + (threadIdx.x >> 6);
  int lane = threadIdx.x & 63;
  const float* xr = x + (size_t)t * H_DIM;
  float acc[E_NUM];
#pragma unroll
  for (int e = 0; e < E_NUM; e++) acc[e] = 0.f;
  for (int j = lane; j < H_DIM; j += 64) {
    float xv = xr[j];
#pragma unroll
    for (int e = 0; e < E_NUM; e++) acc[e] += xv * rw[e * H_DIM + j];
  }
#pragma unroll
  for (int e = 0; e < E_NUM; e++) {
    float v = acc[e];
#pragma unroll
    for (int s = 32; s > 0; s >>= 1) v += __shfl_xor(v, s);
    acc[e] = v;
  }
  if (lane == 0) {
    // top-2 selection on exact fp32 logits (stable: first index wins ties)
    int i0 = 0;
#pragma unroll
    for (int e = 1; e < E_NUM; e++) if (acc[e] > acc[i0]) i0 = e;
    int i1 = (i0 == 0) ? 1 : 0;
#pragma unroll
    for (int e = 0; e < E_NUM; e++) if (e != i0 && acc[e] > acc[i1]) i1 = e;
    float mx = acc[0];
#pragma unroll
    for (int e = 1; e < E_NUM; e++) mx = fmaxf(mx, acc[e]);
    float sum = 0.f, p[E_NUM];
#pragma unroll
    for (int e = 0; e < E_NUM; e++) { p[e] = expf(acc[e] - mx); sum += p[e]; }
    float inv = 1.f / sum;
    topk_idx[t * 2] = i0;  topk_idx[t * 2 + 1] = i1;
    topk_w[t * 2] = p[i0] * inv;  topk_w[t * 2 + 1] = p[i1] * inv;
    atomicAdd(&meta[i0], 1);
    atomicAdd(&meta[i1], 1);
  }
}

// ---------------- scan: offsets (BM-aligned), tile table, pad rows ---------
__global__ void scan_kernel(int* __restrict__ meta, int* __restrict__ row_token,
                            float* __restrict__ row_gate) {
  __shared__ int s_off[E_NUM + 1];
  if (threadIdx.x == 0) {
    int o = 0, nt = 0;
    for (int e = 0; e < E_NUM; e++) {
      meta[16 + e] = o; s_off[e] = o;
      int c = meta[e];
      int mtc = (c + BM - 1) / BM;
      for (int m = 0; m < mtc; m++) { meta[64 + nt] = e; meta[256 + nt] = o + m * BM; nt++; }
      o += mtc * BM;
      meta[8 + e] = 0; // cursor
    }
    meta[16 + E_NUM] = o; s_off[E_NUM] = o;
    meta[32] = nt;
  }
  __syncthreads();
  for (int e = 0; e < E_NUM; e++) {
    int lo = s_off[e] + meta[e], hi = s_off[e + 1];
    for (int r = lo + (int)threadIdx.x; r < hi; r += 64) { row_token[r] = -1; row_gate[r] = 0.f; }
  }
}

// ---------------- bucket: scatter (token,k) -> permuted row ----------------
__global__ __launch_bounds__(256) void bucket_kernel(
    const int* __restrict__ topk_idx, const float* __restrict__ topk_w,
    int* __restrict__ meta, int* __restrict__ row_token, float* __restrict__ row_gate) {
  int i = blockIdx.x * 256 + threadIdx.x;
  if (i >= 2 * T_TOK) return;
  int e = topk_idx[i];
  int pos = atomicAdd(&meta[8 + e], 1);
  int r = meta[16 + e] + pos;
  row_token[r] = i >> 1;
  row_gate[r] = topk_w[i];
}

// ---------------- straight fp32 -> bf16 convert (x) ------------------------
__global__ __launch_bounds__(256) void cvt_kernel(const float* __restrict__ in,
                                                  unsigned short* __restrict__ out, int n) {
  int i = (blockIdx.x * 256 + threadIdx.x) * 8;
  if (i >= n) return;
  ushort8 v;
#pragma unroll
  for (int j = 0; j < 8; j++) v[j] = f2bf(in[i + j]);
  *(ushort8*)(out + i) = v;
}

// ---------------- transpose + convert: [R][C] fp32 -> [C][R] bf16 ----------
__global__ __launch_bounds__(256) void tcvt_kernel(const float* __restrict__ in,
                                                   unsigned short* __restrict__ out,
                                                   int R, int C) {
  __shared__ unsigned short tile[64][66];
  size_t ebase = (size_t)blockIdx.z * (size_t)R * (size_t)C;
  const float* src = in + ebase;
  unsigned short* dst = out + ebase;
  int c0 = blockIdx.x * 64, r0 = blockIdx.y * 64;
  int tx = threadIdx.x & 63, ty = threadIdx.x >> 6;
#pragma unroll
  for (int rr = ty; rr < 64; rr += 4)
    tile[rr][tx] = f2bf(src[(size_t)(r0 + rr) * C + c0 + tx]);
  __syncthreads();
#pragma unroll
  for (int cc = ty; cc < 64; cc += 4)
    dst[(size_t)(c0 + cc) * R + r0 + tx] = tile[tx][cc];
}

// ---------------- GEMM1: h = silu(x@Wg) * (x@Wu), grouped, bf16 ------------
__global__ __launch_bounds__(256) void gemm1_kernel(
    const unsigned short* __restrict__ xb,   // [T][H] bf16
    const unsigned short* __restrict__ wgu,  // [E][2I][H] bf16 (transposed)
    unsigned short* __restrict__ hbuf,       // [ROWS_CAP][I] bf16
    const int* __restrict__ row_token, const int* __restrict__ meta) {
  if ((int)blockIdx.y >= meta[32]) return;
  int e = meta[64 + blockIdx.y];
  int row0 = meta[256 + blockIdx.y];
  int n0 = blockIdx.x * BN; // within I

  __shared__ alignas(16) unsigned short sA[BM * BK];
  __shared__ alignas(16) unsigned short sG[BM * BK];
  __shared__ alignas(16) unsigned short sU[BM * BK];

  int tid = threadIdx.x, lane = tid & 63, wid = tid >> 6;
  int c8 = (tid & 7) * 8;
  const unsigned short* asrc[4];
  const unsigned short* gsrc[4];
  const unsigned short* usrc[4];
  {
    const unsigned short* wb = wgu + (size_t)e * (2 * (size_t)I_DIM) * H_DIM;
#pragma unroll
    for (int i = 0; i < 4; i++) {
      int r = i * 32 + (tid >> 3);
      int tok = row_token[row0 + r];
      if (tok < 0) tok = 0;
      asrc[i] = xb + (size_t)tok * H_DIM + c8;
      gsrc[i] = wb + (size_t)(n0 + r) * H_DIM + c8;
      usrc[i] = wb + (size_t)(I_DIM + n0 + r) * H_DIM + c8;
    }
  }
  f32x4 accG[4][4] = {};
  f32x4 accU[4][4] = {};

  for (int kt = 0; kt < H_DIM / BK; kt++) {
    int kof = kt * BK;
#pragma unroll
    for (int i = 0; i < 4; i++) {
      gld_lds16(asrc[i] + kof, (char*)sA + i * 4096 + wid * 1024);
      gld_lds16(gsrc[i] + kof, (char*)sG + i * 4096 + wid * 1024);
      gld_lds16(usrc[i] + kof, (char*)sU + i * 4096 + wid * 1024);
    }
    __syncthreads();
    int mrow = (wid >> 1) * 64 + (lane & 15);
    int brow = (wid & 1) * 64 + (lane & 15);
#pragma unroll
    for (int kk = 0; kk < 2; kk++) {
      int krd = kk * 32 + (lane >> 4) * 8;
      short8 af[4], gf[4], uf[4];
#pragma unroll
      for (int f = 0; f < 4; f++) {
        af[f] = *(const short8*)(sA + (mrow + f * 16) * BK + krd);
        gf[f] = *(const short8*)(sG + (brow + f * 16) * BK + krd);
        uf[f] = *(const short8*)(sU + (brow + f * 16) * BK + krd);
      }
#pragma unroll
      for (int fm = 0; fm < 4; fm++)
#pragma unroll
        for (int fn = 0; fn < 4; fn++) {
          accG[fm][fn] = __builtin_amdgcn_mfma_f32_16x16x32_bf16(af[fm], gf[fn], accG[fm][fn], 0, 0, 0);
          accU[fm][fn] = __builtin_amdgcn_mfma_f32_16x16x32_bf16(af[fm], uf[fn], accU[fm][fn], 0, 0, 0);
        }
    }
    __syncthreads();
  }
  // epilogue: SwiGLU, store bf16 h
  int m0 = (wid >> 1) * 64;
  int cc0 = n0 + (wid & 1) * 64 + (lane & 15);
#pragma unroll
  for (int fm = 0; fm < 4; fm++)
#pragma unroll
    for (int r = 0; r < 4; r++) {
      size_t rbase = (size_t)(row0 + m0 + fm * 16 + (lane >> 4) * 4 + r) * I_DIM;
#pragma unroll
      for (int fn = 0; fn < 4; fn++) {
        float g = accG[fm][fn][r], u = accU[fm][fn][r];
        float hv = (g / (1.f + __expf(-g))) * u;
        hbuf[rbase + cc0 + fn * 16] = f2bf(hv);
      }
    }
}

// ---------------- GEMM2: out[token] += gate * (h @ Wd), grouped ------------
__global__ __launch_bounds__(256) void gemm2_kernel(
    const unsigned short* __restrict__ hbuf, // [ROWS_CAP][I] bf16
    const unsigned short* __restrict__ wd,   // [E][H][I] bf16 (transposed)
    float* __restrict__ out,
    const int* __restrict__ row_token, const float* __restrict__ row_gate,
    const int* __restrict__ meta) {
  if ((int)blockIdx.y >= meta[32]) return;
  int e = meta[64 + blockIdx.y];
  int row0 = meta[256 + blockIdx.y];
  int n0 = blockIdx.x * BN; // within H

  __shared__ alignas(16) unsigned short sA[BM * BK];
  __shared__ alignas(16) unsigned short sB[BM * BK];

  int tid = threadIdx.x, lane = tid & 63, wid = tid >> 6;
  int c8 = (tid & 7) * 8;
  const unsigned short* asrc[4];
  const unsigned short* bsrc[4];
  {
    const unsigned short* wb = wd + (size_t)e * (size_t)H_DIM * I_DIM;
#pragma unroll
    for (int i = 0; i < 4; i++) {
      int r = i * 32 + (tid >> 3);
      asrc[i] = hbuf + (size_t)(row0 + r) * I_DIM + c8;
      bsrc[i] = wb + (size_t)(n0 + r) * I_DIM + c8;
    }
  }
  f32x4 acc[4][4] = {};

  for (int kt = 0; kt < I_DIM / BK; kt++) {
    int kof = kt * BK;
#pragma unroll
    for (int i = 0; i < 4; i++) {
      gld_lds16(asrc[i] + kof, (char*)sA + i * 4096 + wid * 1024);
      gld_lds16(bsrc[i] + kof, (char*)sB + i * 4096 + wid * 1024);
    }
    __syncthreads();
    int mrow = (wid >> 1) * 64 + (lane & 15);
    int brow = (wid & 1) * 64 + (lane & 15);
#pragma unroll
    for (int kk = 0; kk < 2; kk++) {
      int krd = kk * 32 + (lane >> 4) * 8;
      short8 af[4], bf[4];
#pragma unroll
      for (int f = 0; f < 4; f++) {
        af[f] = *(const short8*)(sA + (mrow + f * 16) * BK + krd);
        bf[f] = *(const short8*)(sB + (brow + f * 16) * BK + krd);
      }
#pragma unroll
      for (int fm = 0; fm < 4; fm++)
#pragma unroll
        for (int fn = 0; fn < 4; fn++)
          acc[fm][fn] = __builtin_amdgcn_mfma_f32_16x16x32_bf16(af[fm], bf[fn], acc[fm][fn], 0, 0, 0);
    }
    __syncthreads();
  }
  // epilogue: weighted scatter-add (exactly 2 contributions/out elem -> deterministic)
  int m0 = (wid >> 1) * 64;
  int nn0 = n0 + (wid & 1) * 64 + (lane & 15);
#pragma unroll
  for (int fm = 0; fm < 4; fm++)
#pragma unroll
    for (int r = 0; r < 4; r++) {
      int rr = row0 + m0 + fm * 16 + (lane >> 4) * 4 + r;
      int tok = row_token[rr];
      if (tok < 0) continue;
      float gate = row_gate[rr];
      float* orow = out + (size_t)tok * H_DIM + nn0;
#pragma unroll
      for (int fn = 0; fn < 4; fn++)
        atomicAdd(orow + fn * 16, gate * acc[fm][fn][r]);
    }
}

extern "C" void kernel_launch(void* const* d_in, const int* in_sizes, int n_in,
                              void* d_out, int out_size, void* d_ws, size_t ws_size,
                              hipStream_t stream) {
  const float* x   = (const float*)d_in[0];
  const float* rw  = (const float*)d_in[1];
  const float* wgu = (const float*)d_in[2];
  const float* wdn = (const float*)d_in[3];
  float* out = (float*)d_out;

  char* ws = (char*)d_ws;
  size_t off = 0;
  auto alloc = [&](size_t bytes) {
    void* p = ws + off;
    off += (bytes + 255) & ~(size_t)255;
    return p;
  };
  int* meta            = (int*)alloc(4096);
  int* topk_idx        = (int*)alloc((size_t)2 * T_TOK * 4);
  float* topk_w        = (float*)alloc((size_t)2 * T_TOK * 4);
  int* row_token       = (int*)alloc((size_t)ROWS_CAP * 4);
  float* row_gate      = (float*)alloc((size_t)ROWS_CAP * 4);
  unsigned short* xb    = (unsigned short*)alloc((size_t)T_TOK * H_DIM * 2);
  unsigned short* wgu_t = (unsigned short*)alloc((size_t)E_NUM * 2 * I_DIM * H_DIM * 2);
  unsigned short* wd_t  = (unsigned short*)alloc((size_t)E_NUM * H_DIM * I_DIM * 2);
  unsigned short* hbuf  = (unsigned short*)alloc((size_t)ROWS_CAP * I_DIM * 2);

  if (off > ws_size) { // workspace too small: fail loudly (zero output)
    hipMemsetAsync(d_out, 0, (size_t)out_size * sizeof(float), stream);
    return;
  }

  hipMemsetAsync(meta, 0, 4096, stream);
  hipMemsetAsync(d_out, 0, (size_t)out_size * sizeof(float), stream);

  // conversions
  cvt_kernel<<<(T_TOK * H_DIM / 8 + 255) / 256, 256, 0, stream>>>(x, xb, T_TOK * H_DIM);
  tcvt_kernel<<<dim3(2 * I_DIM / 64, H_DIM / 64, E_NUM), 256, 0, stream>>>(wgu, wgu_t, H_DIM, 2 * I_DIM);
  tcvt_kernel<<<dim3(H_DIM / 64, I_DIM / 64, E_NUM), 256, 0, stream>>>(wdn, wd_t, I_DIM, H_DIM);

  // routing
  router_kernel<<<T_TOK / 4, 256, 0, stream>>>(x, rw, topk_idx, topk_w, meta);
  scan_kernel<<<1, 64, 0, stream>>>(meta, row_token, row_gate);
  bucket_kernel<<<(2 * T_TOK + 255) / 256, 256, 0, stream>>>(topk_idx, topk_w, meta, row_token, row_gate);

  // grouped expert MLP
  gemm1_kernel<<<dim3(I_DIM / BN, MAX_MT), 256, 0, stream>>>(xb, wgu_t, hbuf, row_token, meta);
  gemm2_kernel<<<dim3(H_DIM / BN, MAX_MT), 256, 0, stream>>>(hbuf, wd_t, out, row_token, row_gate, meta);
}

// Round 3
// 935.931 us; speedup vs baseline: 1.2109x; 1.2109x over previous
//
#include <hip/hip_runtime.h>
#include <hip/hip_bf16.h>
#include <cstdint>
#include <cstddef>

#define T_TOK 8192
#define H_DIM 2048
#define I_DIM 1408
#define E_NUM 8
#define BM 128
#define BK 64
#define ROWS_CAP (2 * T_TOK + E_NUM * BM) /* 17408 */
#define MAX_MT (ROWS_CAP / BM)            /* 136 */
#define NT1 (I_DIM / 64)                  /* 22: gemm1 N-tiles (64 gate + 64 up cols each) */
#define NT2 (H_DIM / 128)                 /* 16: gemm2 N-tiles */

typedef __attribute__((ext_vector_type(8))) short short8;
typedef __attribute__((ext_vector_type(4))) float f32x4;
typedef __attribute__((ext_vector_type(8))) unsigned short ushort8;

static __device__ __forceinline__ unsigned short f2bf(float f) {
  unsigned u = __float_as_uint(f);
  u += 0x7FFFu + ((u >> 16) & 1u);   // round-to-nearest-even
  return (unsigned short)(u >> 16);
}

static __device__ __forceinline__ void gld_lds16(const void* g, void* l) {
  __builtin_amdgcn_global_load_lds(
      (__attribute__((address_space(1))) unsigned int*)g,
      (__attribute__((address_space(3))) unsigned int*)l, 16, 0, 0);
}

// XCD-chunked bijective remap (nb % 8 == 0 by construction) + intra order:
// M-groups of 4 (slowest), N (middle), M-in-group (fastest) -> L2 reuse of
// both the A-tiles (2MB/group) and the B panel (reused x4 back-to-back).
static __device__ __forceinline__ void remap_tile(int bid, int nb, int nt_cols,
                                                  int& m_t, int& n_t) {
  int chunk = nb >> 3;
  int wg = (bid & 7) * chunk + (bid >> 3);
  int grp = wg / (nt_cols * 4);
  int rem = wg % (nt_cols * 4);
  n_t = rem >> 2;
  m_t = grp * 4 + (rem & 3);
}

// ---------------- router: fp32 logits, softmax, top-2, expert histogram ----
__global__ __launch_bounds__(256) void router_kernel(
    const float* __restrict__ x, const float* __restrict__ rw,
    int* __restrict__ topk_idx, float* __restrict__ topk_w, int* __restrict__ meta) {
  int t = blockIdx.x * 4 + (threadIdx.x >> 6);
  int lane = threadIdx.x & 63;
  const float* xr = x + (size_t)t * H_DIM;
  float acc[E_NUM];
#pragma unroll
  for (int e = 0; e < E_NUM; e++) acc[e] = 0.f;
  for (int j = lane; j < H_DIM; j += 64) {
    float xv = xr[j];
#pragma unroll
    for (int e = 0; e < E_NUM; e++) acc[e] += xv * rw[e * H_DIM + j];
  }
#pragma unroll
  for (int e = 0; e < E_NUM; e++) {
    float v = acc[e];
#pragma unroll
    for (int s = 32; s > 0; s >>= 1) v += __shfl_xor(v, s);
    acc[e] = v;
  }
  if (lane == 0) {
    int i0 = 0;
#pragma unroll
    for (int e = 1; e < E_NUM; e++) if (acc[e] > acc[i0]) i0 = e;
    int i1 = (i0 == 0) ? 1 : 0;
#pragma unroll
    for (int e = 0; e < E_NUM; e++) if (e != i0 && acc[e] > acc[i1]) i1 = e;
    float mx = acc[0];
#pragma unroll
    for (int e = 1; e < E_NUM; e++) mx = fmaxf(mx, acc[e]);
    float sum = 0.f, p[E_NUM];
#pragma unroll
    for (int e = 0; e < E_NUM; e++) { p[e] = expf(acc[e] - mx); sum += p[e]; }
    float inv = 1.f / sum;
    topk_idx[t * 2] = i0;  topk_idx[t * 2 + 1] = i1;
    topk_w[t * 2] = p[i0] * inv;  topk_w[t * 2 + 1] = p[i1] * inv;
    atomicAdd(&meta[i0], 1);
    atomicAdd(&meta[i1], 1);
  }
}

// ---------------- scan: offsets (BM-aligned), tile table, pad rows ---------
__global__ void scan_kernel(int* __restrict__ meta, int* __restrict__ row_token,
                            float* __restrict__ row_gate) {
  __shared__ int s_off[E_NUM + 1];
  if (threadIdx.x == 0) {
    int o = 0, nt = 0;
    for (int e = 0; e < E_NUM; e++) {
      meta[16 + e] = o; s_off[e] = o;
      int c = meta[e];
      int mtc = (c + BM - 1) / BM;
      for (int m = 0; m < mtc; m++) { meta[64 + nt] = e; meta[256 + nt] = o + m * BM; nt++; }
      o += mtc * BM;
      meta[8 + e] = 0; // cursor
    }
    meta[16 + E_NUM] = o; s_off[E_NUM] = o;
    meta[32] = nt;
  }
  __syncthreads();
  for (int e = 0; e < E_NUM; e++) {
    int lo = s_off[e] + meta[e], hi = s_off[e + 1];
    for (int r = lo + (int)threadIdx.x; r < hi; r += 64) { row_token[r] = -1; row_gate[r] = 0.f; }
  }
}

// ---------------- bucket: scatter (token,k) -> permuted row ----------------
__global__ __launch_bounds__(256) void bucket_kernel(
    const int* __restrict__ topk_idx, const float* __restrict__ topk_w,
    int* __restrict__ meta, int* __restrict__ row_token, float* __restrict__ row_gate) {
  int i = blockIdx.x * 256 + threadIdx.x;
  if (i >= 2 * T_TOK) return;
  int e = topk_idx[i];
  int pos = atomicAdd(&meta[8 + e], 1);
  int r = meta[16 + e] + pos;
  row_token[r] = i >> 1;
  row_gate[r] = topk_w[i];
}

// ---------------- straight fp32 -> bf16 convert (x) ------------------------
__global__ __launch_bounds__(256) void cvt_kernel(const float* __restrict__ in,
                                                  unsigned short* __restrict__ out, int n) {
  int i = (blockIdx.x * 256 + threadIdx.x) * 8;
  if (i >= n) return;
  ushort8 v;
#pragma unroll
  for (int j = 0; j < 8; j++) v[j] = f2bf(in[i + j]);
  *(ushort8*)(out + i) = v;
}

// ---------------- transpose + convert: [R][C] fp32 -> [C][R] bf16 ----------
__global__ __launch_bounds__(256) void tcvt_kernel(const float* __restrict__ in,
                                                   unsigned short* __restrict__ out,
                                                   int R, int C) {
  __shared__ unsigned short tile[64][66];
  size_t ebase = (size_t)blockIdx.z * (size_t)R * (size_t)C;
  const float* src = in + ebase;
  unsigned short* dst = out + ebase;
  int c0 = blockIdx.x * 64, r0 = blockIdx.y * 64;
  int tx = threadIdx.x & 63, ty = threadIdx.x >> 6;
#pragma unroll
  for (int rr = ty; rr < 64; rr += 4)
    tile[rr][tx] = f2bf(src[(size_t)(r0 + rr) * C + c0 + tx]);
  __syncthreads();
#pragma unroll
  for (int cc = ty; cc < 64; cc += 4)
    dst[(size_t)(c0 + cc) * R + r0 + tx] = tile[tx][cc];
}

// ---------------- GEMM1: h = silu(x@Wg) * (x@Wu), grouped, m97 shape -------
// B tile stacks 64 gate rows (LDS rows 0-63) + 64 up rows (64-127); waves
// with (wid&1)==0 accumulate gate, (wid&1)==1 accumulate up for the SAME
// 64 h-columns; SwiGLU combine via post-loop LDS exchange.
__global__ __launch_bounds__(256) void gemm1_kernel(
    const unsigned short* __restrict__ xb,   // [T][H] bf16
    const unsigned short* __restrict__ wgu,  // [E][2I][H] bf16 (transposed)
    unsigned short* __restrict__ hbuf,       // [ROWS_CAP][I] bf16
    const int* __restrict__ row_token, const int* __restrict__ meta) {
  int m_t, n_t;
  remap_tile(blockIdx.x, NT1 * MAX_MT, NT1, m_t, n_t);
  if (m_t >= meta[32]) return;
  int e = meta[64 + m_t];
  int row0 = meta[256 + m_t];
  int n0h = n_t * 64;  // h-column base

  __shared__ alignas(16) char smem[32768];
  unsigned short* sA = (unsigned short*)smem;            // [128][64]
  unsigned short* sB = (unsigned short*)(smem + 16384);  // [128][64]

  int tid = threadIdx.x, lane = tid & 63, wid = tid >> 6;
  const unsigned short* asrc[4];
  const unsigned short* bsrc[4];
  {
    const unsigned short* wb = wgu + (size_t)e * (2 * (size_t)I_DIM) * H_DIM;
#pragma unroll
    for (int i = 0; i < 4; i++) {
      int r = i * 32 + (tid >> 3);
      int ch = ((tid & 7) ^ (r & 7)) * 8;  // inverse-swizzled source chunk
      int tok = row_token[row0 + r];
      if (tok < 0) tok = 0;
      asrc[i] = xb + (size_t)tok * H_DIM + ch;
      int wr = (r < 64) ? (n0h + r) : (I_DIM + n0h + (r - 64));
      bsrc[i] = wb + (size_t)wr * H_DIM + ch;
    }
  }
  f32x4 acc[4][4] = {};
  int mrow = (wid >> 1) * 64 + (lane & 15);
  int brow = (wid & 1) * 64 + (lane & 15);

  for (int kt = 0; kt < H_DIM / BK; kt++) {
    int kof = kt * BK;
#pragma unroll
    for (int i = 0; i < 4; i++) {
      gld_lds16(asrc[i] + kof, smem + i * 4096 + wid * 1024);
      gld_lds16(bsrc[i] + kof, smem + 16384 + i * 4096 + wid * 1024);
    }
    __syncthreads();
#pragma unroll
    for (int kk = 0; kk < 2; kk++) {
      int krd = ((kk * 4 + (lane >> 4)) ^ (lane & 7)) * 8;  // swizzled read chunk
      short8 af[4], bf[4];
#pragma unroll
      for (int f = 0; f < 4; f++) {
        af[f] = *(const short8*)(sA + (mrow + f * 16) * BK + krd);
        bf[f] = *(const short8*)(sB + (brow + f * 16) * BK + krd);
      }
#pragma unroll
      for (int fm = 0; fm < 4; fm++)
#pragma unroll
        for (int fn = 0; fn < 4; fn++)
          acc[fm][fn] = __builtin_amdgcn_mfma_f32_16x16x32_bf16(af[fm], bf[fn], acc[fm][fn], 0, 0, 0);
    }
    __syncthreads();
  }

  // ---- SwiGLU epilogue: odd waves (U) publish via LDS, even waves combine.
  float* xch = (float*)smem;
  float* xw = xch + (wid >> 1) * 4096;  // 64x64 f32 per wave-pair
  if (wid & 1) {
#pragma unroll
    for (int fm = 0; fm < 4; fm++)
#pragma unroll
      for (int r = 0; r < 4; r++) {
        int mloc = fm * 16 + (lane >> 4) * 4 + r;
#pragma unroll
        for (int fn = 0; fn < 4; fn++)
          xw[mloc * 64 + fn * 16 + (lane & 15)] = acc[fm][fn][r];
      }
  }
  __syncthreads();
  if (!(wid & 1)) {
    int mbase = row0 + (wid >> 1) * 64;
#pragma unroll
    for (int fm = 0; fm < 4; fm++)
#pragma unroll
      for (int r = 0; r < 4; r++) {
        int mloc = fm * 16 + (lane >> 4) * 4 + r;
        size_t rbase = (size_t)(mbase + mloc) * I_DIM + n0h;
#pragma unroll
        for (int fn = 0; fn < 4; fn++) {
          float g = acc[fm][fn][r];
          float u = xw[mloc * 64 + fn * 16 + (lane & 15)];
          float hv = (g / (1.f + __expf(-g))) * u;
          hbuf[rbase + fn * 16 + (lane & 15)] = f2bf(hv);
        }
      }
  }
}

// ---------------- GEMM2: out[token] += gate * (h @ Wd), grouped ------------
__global__ __launch_bounds__(256) void gemm2_kernel(
    const unsigned short* __restrict__ hbuf, // [ROWS_CAP][I] bf16
    const unsigned short* __restrict__ wd,   // [E][H][I] bf16 (transposed)
    float* __restrict__ out,
    const int* __restrict__ row_token, const float* __restrict__ row_gate,
    const int* __restrict__ meta) {
  int m_t, n_t;
  remap_tile(blockIdx.x, NT2 * MAX_MT, NT2, m_t, n_t);
  if (m_t >= meta[32]) return;
  int e = meta[64 + m_t];
  int row0 = meta[256 + m_t];
  int n0 = n_t * 128;

  __shared__ alignas(16) char smem[32768];
  unsigned short* sA = (unsigned short*)smem;
  unsigned short* sB = (unsigned short*)(smem + 16384);

  int tid = threadIdx.x, lane = tid & 63, wid = tid >> 6;
  const unsigned short* asrc[4];
  const unsigned short* bsrc[4];
  {
    const unsigned short* wb = wd + (size_t)e * (size_t)H_DIM * I_DIM;
#pragma unroll
    for (int i = 0; i < 4; i++) {
      int r = i * 32 + (tid >> 3);
      int ch = ((tid & 7) ^ (r & 7)) * 8;
      asrc[i] = hbuf + (size_t)(row0 + r) * I_DIM + ch;
      bsrc[i] = wb + (size_t)(n0 + r) * I_DIM + ch;
    }
  }
  f32x4 acc[4][4] = {};
  int mrow = (wid >> 1) * 64 + (lane & 15);
  int brow = (wid & 1) * 64 + (lane & 15);

  for (int kt = 0; kt < I_DIM / BK; kt++) {
    int kof = kt * BK;
#pragma unroll
    for (int i = 0; i < 4; i++) {
      gld_lds16(asrc[i] + kof, smem + i * 4096 + wid * 1024);
      gld_lds16(bsrc[i] + kof, smem + 16384 + i * 4096 + wid * 1024);
    }
    __syncthreads();
#pragma unroll
    for (int kk = 0; kk < 2; kk++) {
      int krd = ((kk * 4 + (lane >> 4)) ^ (lane & 7)) * 8;
      short8 af[4], bf[4];
#pragma unroll
      for (int f = 0; f < 4; f++) {
        af[f] = *(const short8*)(sA + (mrow + f * 16) * BK + krd);
        bf[f] = *(const short8*)(sB + (brow + f * 16) * BK + krd);
      }
#pragma unroll
      for (int fm = 0; fm < 4; fm++)
#pragma unroll
        for (int fn = 0; fn < 4; fn++)
          acc[fm][fn] = __builtin_amdgcn_mfma_f32_16x16x32_bf16(af[fm], bf[fn], acc[fm][fn], 0, 0, 0);
    }
    __syncthreads();
  }
  // epilogue: weighted scatter-add (exactly 2 contributions/out elem -> deterministic)
  int m0 = (wid >> 1) * 64;
  int nn0 = n0 + (wid & 1) * 64 + (lane & 15);
#pragma unroll
  for (int fm = 0; fm < 4; fm++)
#pragma unroll
    for (int r = 0; r < 4; r++) {
      int rr = row0 + m0 + fm * 16 + (lane >> 4) * 4 + r;
      int tok = row_token[rr];
      if (tok < 0) continue;
      float gate = row_gate[rr];
      float* orow = out + (size_t)tok * H_DIM + nn0;
#pragma unroll
      for (int fn = 0; fn < 4; fn++)
        atomicAdd(orow + fn * 16, gate * acc[fm][fn][r]);
    }
}

extern "C" void kernel_launch(void* const* d_in, const int* in_sizes, int n_in,
                              void* d_out, int out_size, void* d_ws, size_t ws_size,
                              hipStream_t stream) {
  const float* x   = (const float*)d_in[0];
  const float* rw  = (const float*)d_in[1];
  const float* wgu = (const float*)d_in[2];
  const float* wdn = (const float*)d_in[3];
  float* out = (float*)d_out;

  char* ws = (char*)d_ws;
  size_t off = 0;
  auto alloc = [&](size_t bytes) {
    void* p = ws + off;
    off += (bytes + 255) & ~(size_t)255;
    return p;
  };
  int* meta            = (int*)alloc(4096);
  int* topk_idx        = (int*)alloc((size_t)2 * T_TOK * 4);
  float* topk_w        = (float*)alloc((size_t)2 * T_TOK * 4);
  int* row_token       = (int*)alloc((size_t)ROWS_CAP * 4);
  float* row_gate      = (float*)alloc((size_t)ROWS_CAP * 4);
  unsigned short* xb    = (unsigned short*)alloc((size_t)T_TOK * H_DIM * 2);
  unsigned short* wgu_t = (unsigned short*)alloc((size_t)E_NUM * 2 * I_DIM * H_DIM * 2);
  unsigned short* wd_t  = (unsigned short*)alloc((size_t)E_NUM * H_DIM * I_DIM * 2);
  unsigned short* hbuf  = (unsigned short*)alloc((size_t)ROWS_CAP * I_DIM * 2);

  if (off > ws_size) { // workspace too small: fail loudly (zero output)
    hipMemsetAsync(d_out, 0, (size_t)out_size * sizeof(float), stream);
    return;
  }

  hipMemsetAsync(meta, 0, 4096, stream);
  hipMemsetAsync(d_out, 0, (size_t)out_size * sizeof(float), stream);

  // conversions
  cvt_kernel<<<(T_TOK * H_DIM / 8 + 255) / 256, 256, 0, stream>>>(x, xb, T_TOK * H_DIM);
  tcvt_kernel<<<dim3(2 * I_DIM / 64, H_DIM / 64, E_NUM), 256, 0, stream>>>(wgu, wgu_t, H_DIM, 2 * I_DIM);
  tcvt_kernel<<<dim3(H_DIM / 64, I_DIM / 64, E_NUM), 256, 0, stream>>>(wdn, wd_t, I_DIM, H_DIM);

  // routing
  router_kernel<<<T_TOK / 4, 256, 0, stream>>>(x, rw, topk_idx, topk_w, meta);
  scan_kernel<<<1, 64, 0, stream>>>(meta, row_token, row_gate);
  bucket_kernel<<<(2 * T_TOK + 255) / 256, 256, 0, stream>>>(topk_idx, topk_w, meta, row_token, row_gate);

  // grouped expert MLP
  gemm1_kernel<<<NT1 * MAX_MT, 256, 0, stream>>>(xb, wgu_t, hbuf, row_token, meta);
  gemm2_kernel<<<NT2 * MAX_MT, 256, 0, stream>>>(hbuf, wd_t, out, row_token, row_gate, meta);
}

// Round 5
// 776.658 us; speedup vs baseline: 1.4592x; 1.2051x over previous
//
#include <hip/hip_runtime.h>
#include <hip/hip_bf16.h>
#include <cstdint>
#include <cstddef>

#define T_TOK 8192
#define H_DIM 2048
#define I_DIM 1408
#define E_NUM 8
#define BM 128
#define BK 64
#define ROWS_CAP (2 * T_TOK + E_NUM * BM) /* 17408 */
#define MAX_MT (ROWS_CAP / BM)            /* 136 */
#define NT1 (I_DIM / 64)                  /* 22 */
#define NT2 (H_DIM / 128)                 /* 16 */

typedef __attribute__((ext_vector_type(8))) short short8;
typedef __attribute__((ext_vector_type(4))) float f32x4;
typedef __attribute__((ext_vector_type(8))) unsigned short bf16x8;
typedef __attribute__((ext_vector_type(4))) unsigned short bf16x4;
typedef __attribute__((ext_vector_type(8))) _Float16 h16x8;

static __device__ __forceinline__ unsigned short f2bf(float f) {
  unsigned u = __float_as_uint(f);
  u += 0x7FFFu + ((u >> 16) & 1u);   // round-to-nearest-even
  return (unsigned short)(u >> 16);
}

static __device__ __forceinline__ void gld_lds16(const void* g, void* l) {
  __builtin_amdgcn_global_load_lds(
      (__attribute__((address_space(1))) unsigned int*)g,
      (__attribute__((address_space(3))) unsigned int*)l, 16, 0, 0);
}

// XCD-chunked bijective remap (nb % 8 == 0) + M-groups-of-4 intra order.
static __device__ __forceinline__ void remap_tile(int bid, int nb, int nt_cols,
                                                  int& m_t, int& n_t) {
  int chunk = nb >> 3;
  int wg = (bid & 7) * chunk + (bid >> 3);
  int grp = wg / (nt_cols * 4);
  int rem = wg % (nt_cols * 4);
  n_t = rem >> 2;
  m_t = grp * 4 + (rem & 3);
}

// ---------------- router ---------------------------------------------------
__global__ __launch_bounds__(256) void router_kernel(
    const float* __restrict__ x, const float* __restrict__ rw,
    int* __restrict__ topk_idx, float* __restrict__ topk_w, int* __restrict__ meta) {
  int t = blockIdx.x * 4 + (threadIdx.x >> 6);
  int lane = threadIdx.x & 63;
  const float* xr = x + (size_t)t * H_DIM;
  float acc[E_NUM];
#pragma unroll
  for (int e = 0; e < E_NUM; e++) acc[e] = 0.f;
  for (int j = lane; j < H_DIM; j += 64) {
    float xv = xr[j];
#pragma unroll
    for (int e = 0; e < E_NUM; e++) acc[e] += xv * rw[e * H_DIM + j];
  }
#pragma unroll
  for (int e = 0; e < E_NUM; e++) {
    float v = acc[e];
#pragma unroll
    for (int s = 32; s > 0; s >>= 1) v += __shfl_xor(v, s);
    acc[e] = v;
  }
  if (lane == 0) {
    int i0 = 0;
#pragma unroll
    for (int e = 1; e < E_NUM; e++) if (acc[e] > acc[i0]) i0 = e;
    int i1 = (i0 == 0) ? 1 : 0;
#pragma unroll
    for (int e = 0; e < E_NUM; e++) if (e != i0 && acc[e] > acc[i1]) i1 = e;
    float mx = acc[0];
#pragma unroll
    for (int e = 1; e < E_NUM; e++) mx = fmaxf(mx, acc[e]);
    float sum = 0.f, p[E_NUM];
#pragma unroll
    for (int e = 0; e < E_NUM; e++) { p[e] = expf(acc[e] - mx); sum += p[e]; }
    float inv = 1.f / sum;
    topk_idx[t * 2] = i0;  topk_idx[t * 2 + 1] = i1;
    topk_w[t * 2] = p[i0] * inv;  topk_w[t * 2 + 1] = p[i1] * inv;
    atomicAdd(&meta[i0], 1);
    atomicAdd(&meta[i1], 1);
  }
}

// ---------------- scan -----------------------------------------------------
__global__ void scan_kernel(int* __restrict__ meta, int* __restrict__ row_token) {
  __shared__ int s_off[E_NUM + 1];
  if (threadIdx.x == 0) {
    int o = 0, nt = 0;
    for (int e = 0; e < E_NUM; e++) {
      meta[16 + e] = o; s_off[e] = o;
      int c = meta[e];
      int mtc = (c + BM - 1) / BM;
      for (int m = 0; m < mtc; m++) { meta[64 + nt] = e; meta[256 + nt] = o + m * BM; nt++; }
      o += mtc * BM;
      meta[8 + e] = 0; // cursor
    }
    meta[16 + E_NUM] = o; s_off[E_NUM] = o;
    meta[32] = nt;
  }
  __syncthreads();
  for (int e = 0; e < E_NUM; e++) {
    int lo = s_off[e] + meta[e], hi = s_off[e + 1];
    for (int r = lo + (int)threadIdx.x; r < hi; r += 64) row_token[r] = -1;
  }
}

// ---------------- bucket ---------------------------------------------------
__global__ __launch_bounds__(256) void bucket_kernel(
    const int* __restrict__ topk_idx, int* __restrict__ meta,
    int* __restrict__ row_token, int* __restrict__ tok2row) {
  int i = blockIdx.x * 256 + threadIdx.x;
  if (i >= 2 * T_TOK) return;
  int e = topk_idx[i];
  int pos = atomicAdd(&meta[8 + e], 1);
  int r = meta[16 + e] + pos;
  row_token[r] = i >> 1;
  tok2row[i] = r;
}

// ---------------- fp32 -> bf16 convert (x) ---------------------------------
__global__ __launch_bounds__(256) void cvt_kernel(const float* __restrict__ in,
                                                  unsigned short* __restrict__ out, int n) {
  int i = (blockIdx.x * 256 + threadIdx.x) * 8;
  if (i >= n) return;
  bf16x8 v;
#pragma unroll
  for (int j = 0; j < 8; j++) v[j] = f2bf(in[i + j]);
  *(bf16x8*)(out + i) = v;
}

// ---------------- transpose+convert: [R][C] fp32 -> [C][R] bf16 ------------
// float4 reads, 4-wide transposed writes; +2 pad -> 2-way LDS (free).
__global__ __launch_bounds__(256) void tcvt_kernel(const float* __restrict__ in,
                                                   unsigned short* __restrict__ out,
                                                   int R, int C) {
  __shared__ unsigned short tile[64][66];
  size_t ebase = (size_t)blockIdx.z * (size_t)R * (size_t)C;
  const float* src = in + ebase;
  unsigned short* dst = out + ebase;
  int c0 = blockIdx.x * 64, r0 = blockIdx.y * 64;
  int tid = threadIdx.x;
  int q = tid & 15, s = tid >> 4;   // q: 16-wide fast index, s: 16 slices
#pragma unroll
  for (int it = 0; it < 4; it++) {
    int rr = it * 16 + s;
    f32x4 v = *(const f32x4*)(src + (size_t)(r0 + rr) * C + c0 + q * 4);
#pragma unroll
    for (int j = 0; j < 4; j++) tile[rr][q * 4 + j] = f2bf(v[j]);
  }
  __syncthreads();
#pragma unroll
  for (int it = 0; it < 4; it++) {
    int cc = it * 16 + s;
    bf16x4 v;
#pragma unroll
    for (int j = 0; j < 4; j++) v[j] = tile[q * 4 + j][cc];
    *(bf16x4*)(dst + (size_t)(c0 + cc) * R + r0 + q * 4) = v;
  }
}

// ---------------- GEMM1: h = silu(x@Wg)*(x@Wu), dbuf single-barrier --------
__global__ __launch_bounds__(256) void gemm1_kernel(
    const unsigned short* __restrict__ xb,   // [T][H] bf16
    const unsigned short* __restrict__ wgu,  // [E][2I][H] bf16 (transposed)
    unsigned short* __restrict__ hbuf,       // [ROWS_CAP][I] bf16
    const int* __restrict__ row_token, const int* __restrict__ meta) {
  int m_t, n_t;
  remap_tile(blockIdx.x, NT1 * MAX_MT, NT1, m_t, n_t);
  if (m_t >= meta[32]) return;
  int e = meta[64 + m_t];
  int row0 = meta[256 + m_t];
  int n0h = n_t * 64;

  __shared__ alignas(16) char smem[65536];  // 2 x (A 16K + B 16K)

  int tid = threadIdx.x, lane = tid & 63, wid = tid >> 6;
  const unsigned short* asrc[4];
  const unsigned short* bsrc[4];
  {
    const unsigned short* wb = wgu + (size_t)e * (2 * (size_t)I_DIM) * H_DIM;
#pragma unroll
    for (int i = 0; i < 4; i++) {
      int r = i * 32 + (tid >> 3);
      int ch = ((tid & 7) ^ (r & 7)) * 8;  // inverse-swizzled source chunk
      int tok = row_token[row0 + r];
      if (tok < 0) tok = 0;
      asrc[i] = xb + (size_t)tok * H_DIM + ch;
      int wr = (r < 64) ? (n0h + r) : (I_DIM + n0h + (r - 64));
      bsrc[i] = wb + (size_t)wr * H_DIM + ch;
    }
  }
  f32x4 acc[4][4] = {};
  int mrow = (wid >> 1) * 64 + (lane & 15);
  int brow = (wid & 1) * 64 + (lane & 15);

#define STAGE1(buf, kof_)                                                     \
  {                                                                           \
    int kof = (kof_);                                                         \
    char* b = smem + (buf) * 32768;                                           \
    _Pragma("unroll") for (int i = 0; i < 4; i++) {                           \
      gld_lds16(asrc[i] + kof, b + i * 4096 + wid * 1024);                    \
      gld_lds16(bsrc[i] + kof, b + 16384 + i * 4096 + wid * 1024);            \
    }                                                                         \
  }

  STAGE1(0, 0);
  __syncthreads();
  int cur = 0;
  for (int kt = 0; kt < H_DIM / BK; kt++) {
    if (kt + 1 < H_DIM / BK) STAGE1(cur ^ 1, (kt + 1) * BK);
    const unsigned short* sA = (const unsigned short*)(smem + cur * 32768);
    const unsigned short* sB = sA + 8192;
#pragma unroll
    for (int kk = 0; kk < 2; kk++) {
      int krd = ((kk * 4 + (lane >> 4)) ^ (lane & 7)) * 8;
      short8 af[4], bf[4];
#pragma unroll
      for (int f = 0; f < 4; f++) {
        af[f] = *(const short8*)(sA + (mrow + f * 16) * BK + krd);
        bf[f] = *(const short8*)(sB + (brow + f * 16) * BK + krd);
      }
#pragma unroll
      for (int fm = 0; fm < 4; fm++)
#pragma unroll
        for (int fn = 0; fn < 4; fn++)
          acc[fm][fn] = __builtin_amdgcn_mfma_f32_16x16x32_bf16(af[fm], bf[fn], acc[fm][fn], 0, 0, 0);
    }
    __syncthreads();  // implicit vmcnt(0)+lgkmcnt(0) drain AFTER compute
    cur ^= 1;
  }

  // SwiGLU epilogue: odd waves (U) publish via LDS, even waves combine.
  float* xw = (float*)smem + (wid >> 1) * 4096;  // 64x64 f32 per wave-pair
  if (wid & 1) {
#pragma unroll
    for (int fm = 0; fm < 4; fm++)
#pragma unroll
      for (int r = 0; r < 4; r++) {
        int mloc = fm * 16 + (lane >> 4) * 4 + r;
#pragma unroll
        for (int fn = 0; fn < 4; fn++)
          xw[mloc * 64 + fn * 16 + (lane & 15)] = acc[fm][fn][r];
      }
  }
  __syncthreads();
  if (!(wid & 1)) {
    int mbase = row0 + (wid >> 1) * 64;
#pragma unroll
    for (int fm = 0; fm < 4; fm++)
#pragma unroll
      for (int r = 0; r < 4; r++) {
        int mloc = fm * 16 + (lane >> 4) * 4 + r;
        size_t rbase = (size_t)(mbase + mloc) * I_DIM + n0h;
#pragma unroll
        for (int fn = 0; fn < 4; fn++) {
          float g = acc[fm][fn][r];
          float u = xw[mloc * 64 + fn * 16 + (lane & 15)];
          float hv = (g / (1.f + __expf(-g))) * u;
          hbuf[rbase + fn * 16 + (lane & 15)] = f2bf(hv);
        }
      }
  }
}

// ---------------- GEMM2: part[row] = h @ Wd (f16, un-gated) ----------------
__global__ __launch_bounds__(256) void gemm2_kernel(
    const unsigned short* __restrict__ hbuf, // [ROWS_CAP][I] bf16
    const unsigned short* __restrict__ wd,   // [E][H][I] bf16 (transposed)
    _Float16* __restrict__ part,             // [ROWS_CAP][H] f16
    const int* __restrict__ meta) {
  int m_t, n_t;
  remap_tile(blockIdx.x, NT2 * MAX_MT, NT2, m_t, n_t);
  if (m_t >= meta[32]) return;
  int e = meta[64 + m_t];
  int row0 = meta[256 + m_t];
  int n0 = n_t * 128;

  __shared__ alignas(16) char smem[65536];

  int tid = threadIdx.x, lane = tid & 63, wid = tid >> 6;
  const unsigned short* asrc[4];
  const unsigned short* bsrc[4];
  {
    const unsigned short* wb = wd + (size_t)e * (size_t)H_DIM * I_DIM;
#pragma unroll
    for (int i = 0; i < 4; i++) {
      int r = i * 32 + (tid >> 3);
      int ch = ((tid & 7) ^ (r & 7)) * 8;
      asrc[i] = hbuf + (size_t)(row0 + r) * I_DIM + ch;
      bsrc[i] = wb + (size_t)(n0 + r) * I_DIM + ch;
    }
  }
  f32x4 acc[4][4] = {};
  int mrow = (wid >> 1) * 64 + (lane & 15);
  int brow = (wid & 1) * 64 + (lane & 15);

  STAGE1(0, 0);
  __syncthreads();
  int cur = 0;
  for (int kt = 0; kt < I_DIM / BK; kt++) {
    if (kt + 1 < I_DIM / BK) STAGE1(cur ^ 1, (kt + 1) * BK);
    const unsigned short* sA = (const unsigned short*)(smem + cur * 32768);
    const unsigned short* sB = sA + 8192;
#pragma unroll
    for (int kk = 0; kk < 2; kk++) {
      int krd = ((kk * 4 + (lane >> 4)) ^ (lane & 7)) * 8;
      short8 af[4], bf[4];
#pragma unroll
      for (int f = 0; f < 4; f++) {
        af[f] = *(const short8*)(sA + (mrow + f * 16) * BK + krd);
        bf[f] = *(const short8*)(sB + (brow + f * 16) * BK + krd);
      }
#pragma unroll
      for (int fm = 0; fm < 4; fm++)
#pragma unroll
        for (int fn = 0; fn < 4; fn++)
          acc[fm][fn] = __builtin_amdgcn_mfma_f32_16x16x32_bf16(af[fm], bf[fn], acc[fm][fn], 0, 0, 0);
    }
    __syncthreads();
    cur ^= 1;
  }
  // epilogue: plain f16 stores (no atomics, no gather)
  int m0 = (wid >> 1) * 64;
  int nn0 = n0 + (wid & 1) * 64 + (lane & 15);
#pragma unroll
  for (int fm = 0; fm < 4; fm++)
#pragma unroll
    for (int r = 0; r < 4; r++) {
      int rr = row0 + m0 + fm * 16 + (lane >> 4) * 4 + r;
      _Float16* prow = part + (size_t)rr * H_DIM + nn0;
#pragma unroll
      for (int fn = 0; fn < 4; fn++)
        prow[fn * 16] = (_Float16)acc[fm][fn][r];
    }
}

// ---------------- combine: out[t] = w0*part[r0] + w1*part[r1] --------------
__global__ __launch_bounds__(256) void combine_kernel(
    const _Float16* __restrict__ part, const int* __restrict__ tok2row,
    const float* __restrict__ topk_w, float* __restrict__ out) {
  int t = blockIdx.x;
  int c = threadIdx.x * 8;
  int r0 = tok2row[2 * t], r1 = tok2row[2 * t + 1];
  float w0 = topk_w[2 * t], w1 = topk_w[2 * t + 1];
  h16x8 p0 = *(const h16x8*)(part + (size_t)r0 * H_DIM + c);
  h16x8 p1 = *(const h16x8*)(part + (size_t)r1 * H_DIM + c);
  float* o = out + (size_t)t * H_DIM + c;
  f32x4 lo, hi;
#pragma unroll
  for (int j = 0; j < 4; j++) lo[j] = w0 * (float)p0[j] + w1 * (float)p1[j];
#pragma unroll
  for (int j = 0; j < 4; j++) hi[j] = w0 * (float)p0[4 + j] + w1 * (float)p1[4 + j];
  *(f32x4*)o = lo;
  *(f32x4*)(o + 4) = hi;
}

extern "C" void kernel_launch(void* const* d_in, const int* in_sizes, int n_in,
                              void* d_out, int out_size, void* d_ws, size_t ws_size,
                              hipStream_t stream) {
  const float* x   = (const float*)d_in[0];
  const float* rw  = (const float*)d_in[1];
  const float* wgu = (const float*)d_in[2];
  const float* wdn = (const float*)d_in[3];
  float* out = (float*)d_out;

  char* ws = (char*)d_ws;
  size_t off = 0;
  auto alloc = [&](size_t bytes) {
    void* p = ws + off;
    off += (bytes + 255) & ~(size_t)255;
    return p;
  };
  int* meta            = (int*)alloc(4096);
  int* topk_idx        = (int*)alloc((size_t)2 * T_TOK * 4);
  float* topk_w        = (float*)alloc((size_t)2 * T_TOK * 4);
  int* tok2row         = (int*)alloc((size_t)2 * T_TOK * 4);
  int* row_token       = (int*)alloc((size_t)ROWS_CAP * 4);
  unsigned short* xb    = (unsigned short*)alloc((size_t)T_TOK * H_DIM * 2);
  unsigned short* wgu_t = (unsigned short*)alloc((size_t)E_NUM * 2 * I_DIM * H_DIM * 2);
  unsigned short* wd_t  = (unsigned short*)alloc((size_t)E_NUM * H_DIM * I_DIM * 2);
  unsigned short* hbuf  = (unsigned short*)alloc((size_t)ROWS_CAP * I_DIM * 2);
  // part[ROWS_CAP][H] f16 (71.3 MB) aliases wgu_t (92.3 MB; dead after gemm1)
  _Float16* part = (_Float16*)wgu_t;

  if (off > ws_size) { // workspace too small: fail loudly (zero output)
    (void)hipMemsetAsync(d_out, 0, (size_t)out_size * sizeof(float), stream);
    return;
  }

  (void)hipMemsetAsync(meta, 0, 4096, stream);

  // conversions
  cvt_kernel<<<(T_TOK * H_DIM / 8 + 255) / 256, 256, 0, stream>>>(x, xb, T_TOK * H_DIM);
  tcvt_kernel<<<dim3(2 * I_DIM / 64, H_DIM / 64, E_NUM), 256, 0, stream>>>(wgu, wgu_t, H_DIM, 2 * I_DIM);
  tcvt_kernel<<<dim3(H_DIM / 64, I_DIM / 64, E_NUM), 256, 0, stream>>>(wdn, wd_t, I_DIM, H_DIM);

  // routing
  router_kernel<<<T_TOK / 4, 256, 0, stream>>>(x, rw, topk_idx, topk_w, meta);
  scan_kernel<<<1, 64, 0, stream>>>(meta, row_token);
  bucket_kernel<<<(2 * T_TOK + 255) / 256, 256, 0, stream>>>(topk_idx, meta, row_token, tok2row);

  // grouped expert MLP
  gemm1_kernel<<<NT1 * MAX_MT, 256, 0, stream>>>(xb, wgu_t, hbuf, row_token, meta);
  gemm2_kernel<<<NT2 * MAX_MT, 256, 0, stream>>>(hbuf, wd_t, part, meta);
  combine_kernel<<<T_TOK, 256, 0, stream>>>(part, tok2row, topk_w, out);
}

// Round 6
// 764.562 us; speedup vs baseline: 1.4823x; 1.0158x over previous
//
#include <hip/hip_runtime.h>
#include <hip/hip_bf16.h>
#include <cstdint>
#include <cstddef>

#define T_TOK 8192
#define H_DIM 2048
#define I_DIM 1408
#define E_NUM 8
#define BM 128
#define BK 64
#define ROWS_CAP (2 * T_TOK + E_NUM * BM) /* 17408 */
#define MAX_MT (ROWS_CAP / BM)            /* 136 */
#define NT1 (I_DIM / 64)                  /* 22 */
#define NT2 (H_DIM / 128)                 /* 16 */

typedef __attribute__((ext_vector_type(8))) short short8;
typedef __attribute__((ext_vector_type(4))) float f32x4;
typedef __attribute__((ext_vector_type(8))) unsigned short bf16x8;
typedef __attribute__((ext_vector_type(4))) unsigned short bf16x4;
typedef __attribute__((ext_vector_type(8))) _Float16 h16x8;

static __device__ __forceinline__ unsigned short f2bf(float f) {
  unsigned u = __float_as_uint(f);
  u += 0x7FFFu + ((u >> 16) & 1u);   // round-to-nearest-even
  return (unsigned short)(u >> 16);
}

static __device__ __forceinline__ void gld_lds16(const void* g, void* l) {
  __builtin_amdgcn_global_load_lds(
      (__attribute__((address_space(1))) unsigned int*)g,
      (__attribute__((address_space(3))) unsigned int*)l, 16, 0, 0);
}

// XCD-chunked bijective remap (nb % 8 == 0) + M-groups-of-4 intra order.
static __device__ __forceinline__ void remap_tile(int bid, int nb, int nt_cols,
                                                  int& m_t, int& n_t) {
  int chunk = nb >> 3;
  int wg = (bid & 7) * chunk + (bid >> 3);
  int grp = wg / (nt_cols * 4);
  int rem = wg % (nt_cols * 4);
  n_t = rem >> 2;
  m_t = grp * 4 + (rem & 3);
}

// ---------------- router (fused x->bf16 convert) ---------------------------
__global__ __launch_bounds__(256) void router_kernel(
    const float* __restrict__ x, const float* __restrict__ rw,
    unsigned short* __restrict__ xb,
    int* __restrict__ topk_idx, float* __restrict__ topk_w, int* __restrict__ meta) {
  int t = blockIdx.x * 4 + (threadIdx.x >> 6);
  int lane = threadIdx.x & 63;
  const float* xr = x + (size_t)t * H_DIM;
  unsigned short* xbr = xb + (size_t)t * H_DIM;
  float acc[E_NUM];
#pragma unroll
  for (int e = 0; e < E_NUM; e++) acc[e] = 0.f;
  for (int j = lane * 4; j < H_DIM; j += 256) {
    f32x4 v = *(const f32x4*)(xr + j);
    bf16x4 b;
#pragma unroll
    for (int u = 0; u < 4; u++) b[u] = f2bf(v[u]);
    *(bf16x4*)(xbr + j) = b;
#pragma unroll
    for (int e = 0; e < E_NUM; e++) {
      f32x4 w = *(const f32x4*)(rw + e * H_DIM + j);
      acc[e] += v[0] * w[0] + v[1] * w[1] + v[2] * w[2] + v[3] * w[3];
    }
  }
#pragma unroll
  for (int e = 0; e < E_NUM; e++) {
    float v = acc[e];
#pragma unroll
    for (int s = 32; s > 0; s >>= 1) v += __shfl_xor(v, s);
    acc[e] = v;
  }
  if (lane == 0) {
    int i0 = 0;
#pragma unroll
    for (int e = 1; e < E_NUM; e++) if (acc[e] > acc[i0]) i0 = e;
    int i1 = (i0 == 0) ? 1 : 0;
#pragma unroll
    for (int e = 0; e < E_NUM; e++) if (e != i0 && acc[e] > acc[i1]) i1 = e;
    float mx = acc[0];
#pragma unroll
    for (int e = 1; e < E_NUM; e++) mx = fmaxf(mx, acc[e]);
    float sum = 0.f, p[E_NUM];
#pragma unroll
    for (int e = 0; e < E_NUM; e++) { p[e] = expf(acc[e] - mx); sum += p[e]; }
    float inv = 1.f / sum;
    topk_idx[t * 2] = i0;  topk_idx[t * 2 + 1] = i1;
    topk_w[t * 2] = p[i0] * inv;  topk_w[t * 2 + 1] = p[i1] * inv;
    atomicAdd(&meta[i0], 1);
    atomicAdd(&meta[i1], 1);
  }
}

// ---------------- scan -----------------------------------------------------
__global__ void scan_kernel(int* __restrict__ meta, int* __restrict__ row_token) {
  __shared__ int s_off[E_NUM + 1];
  if (threadIdx.x == 0) {
    int o = 0, nt = 0;
    for (int e = 0; e < E_NUM; e++) {
      meta[16 + e] = o; s_off[e] = o;
      int c = meta[e];
      int mtc = (c + BM - 1) / BM;
      for (int m = 0; m < mtc; m++) { meta[64 + nt] = e; meta[256 + nt] = o + m * BM; nt++; }
      o += mtc * BM;
      meta[8 + e] = 0; // cursor
    }
    meta[16 + E_NUM] = o; s_off[E_NUM] = o;
    meta[32] = nt;
  }
  __syncthreads();
  for (int e = 0; e < E_NUM; e++) {
    int lo = s_off[e] + meta[e], hi = s_off[e + 1];
    for (int r = lo + (int)threadIdx.x; r < hi; r += 64) row_token[r] = -1;
  }
}

// ---------------- bucket ---------------------------------------------------
__global__ __launch_bounds__(256) void bucket_kernel(
    const int* __restrict__ topk_idx, int* __restrict__ meta,
    int* __restrict__ row_token, int* __restrict__ tok2row) {
  int i = blockIdx.x * 256 + threadIdx.x;
  if (i >= 2 * T_TOK) return;
  int e = topk_idx[i];
  int pos = atomicAdd(&meta[8 + e], 1);
  int r = meta[16 + e] + pos;
  row_token[r] = i >> 1;
  tok2row[i] = r;
}

// ---------------- transpose+convert: [R][C] fp32 -> [C][R] bf16 ------------
// f32x4 coalesced reads; transposed scalar LDS fills; bf16x8 (16B/lane)
// coalesced global stores. st rows 72 shorts = 144B (16B-aligned rows).
__global__ __launch_bounds__(256) void tcvt_kernel(const float* __restrict__ in,
                                                   unsigned short* __restrict__ out,
                                                   int R, int C) {
  __shared__ unsigned short st[64][72];
  size_t ebase = (size_t)blockIdx.z * (size_t)R * (size_t)C;
  const float* src = in + ebase;
  unsigned short* dst = out + ebase;
  int c0 = blockIdx.x * 64, r0 = blockIdx.y * 64;
  int tid = threadIdx.x;
  int q = tid & 15, s = tid >> 4;   // q: col quad, s: 16 row slices
#pragma unroll
  for (int it = 0; it < 4; it++) {
    int rr = it * 16 + s;
    f32x4 v = *(const f32x4*)(src + (size_t)(r0 + rr) * C + c0 + q * 4);
#pragma unroll
    for (int j = 0; j < 4; j++) st[q * 4 + j][rr] = f2bf(v[j]);
  }
  __syncthreads();
  int cc = tid >> 3, rseg = (tid & 7) * 8;
#pragma unroll
  for (int it = 0; it < 2; it++) {
    int c = it * 32 + cc;
    bf16x8 v = *(const bf16x8*)(&st[c][rseg]);
    *(bf16x8*)(dst + (size_t)(c0 + c) * R + r0 + rseg) = v;
  }
}

// ---------------- GEMM1: h = silu(x@Wg)*(x@Wu), dbuf single-barrier --------
__global__ __launch_bounds__(256) void gemm1_kernel(
    const unsigned short* __restrict__ xb,   // [T][H] bf16
    const unsigned short* __restrict__ wgu,  // [E][2I][H] bf16 (transposed)
    unsigned short* __restrict__ hbuf,       // [ROWS_CAP][I] bf16
    const int* __restrict__ row_token, const int* __restrict__ meta) {
  int m_t, n_t;
  remap_tile(blockIdx.x, NT1 * MAX_MT, NT1, m_t, n_t);
  if (m_t >= meta[32]) return;
  int e = meta[64 + m_t];
  int row0 = meta[256 + m_t];
  int n0h = n_t * 64;

  __shared__ alignas(16) char smem[65536];  // 2 x (A 16K + B 16K)

  int tid = threadIdx.x, lane = tid & 63, wid = tid >> 6;
  const unsigned short* asrc[4];
  const unsigned short* bsrc[4];
  {
    const unsigned short* wb = wgu + (size_t)e * (2 * (size_t)I_DIM) * H_DIM;
#pragma unroll
    for (int i = 0; i < 4; i++) {
      int r = i * 32 + (tid >> 3);
      int ch = ((tid & 7) ^ (r & 7)) * 8;  // inverse-swizzled source chunk
      int tok = row_token[row0 + r];
      if (tok < 0) tok = 0;
      asrc[i] = xb + (size_t)tok * H_DIM + ch;
      int wr = (r < 64) ? (n0h + r) : (I_DIM + n0h + (r - 64));
      bsrc[i] = wb + (size_t)wr * H_DIM + ch;
    }
  }
  f32x4 acc[4][4] = {};
  int mrow = (wid >> 1) * 64 + (lane & 15);
  int brow = (wid & 1) * 64 + (lane & 15);

#define STAGE1(buf, kof_)                                                     \
  {                                                                           \
    int kof = (kof_);                                                         \
    char* b = smem + (buf) * 32768;                                           \
    _Pragma("unroll") for (int i = 0; i < 4; i++) {                           \
      gld_lds16(asrc[i] + kof, b + i * 4096 + wid * 1024);                    \
      gld_lds16(bsrc[i] + kof, b + 16384 + i * 4096 + wid * 1024);            \
    }                                                                         \
  }

  STAGE1(0, 0);
  __syncthreads();
  int cur = 0;
  for (int kt = 0; kt < H_DIM / BK; kt++) {
    if (kt + 1 < H_DIM / BK) STAGE1(cur ^ 1, (kt + 1) * BK);
    const unsigned short* sA = (const unsigned short*)(smem + cur * 32768);
    const unsigned short* sB = sA + 8192;
#pragma unroll
    for (int kk = 0; kk < 2; kk++) {
      int krd = ((kk * 4 + (lane >> 4)) ^ (lane & 7)) * 8;
      short8 af[4], bf[4];
#pragma unroll
      for (int f = 0; f < 4; f++) {
        af[f] = *(const short8*)(sA + (mrow + f * 16) * BK + krd);
        bf[f] = *(const short8*)(sB + (brow + f * 16) * BK + krd);
      }
#pragma unroll
      for (int fm = 0; fm < 4; fm++)
#pragma unroll
        for (int fn = 0; fn < 4; fn++)
          acc[fm][fn] = __builtin_amdgcn_mfma_f32_16x16x32_bf16(af[fm], bf[fn], acc[fm][fn], 0, 0, 0);
    }
    __syncthreads();
    cur ^= 1;
  }

  // SwiGLU epilogue: odd waves (U) publish via LDS; even waves consume xw
  // into registers (pass 1), then restage bf16 (pass 2) for b128 stores.
  float* xw = (float*)smem + (wid >> 1) * 4096;  // 16KB per wave-pair
  if (wid & 1) {
#pragma unroll
    for (int fm = 0; fm < 4; fm++)
#pragma unroll
      for (int r = 0; r < 4; r++) {
        int mloc = fm * 16 + (lane >> 4) * 4 + r;
#pragma unroll
        for (int fn = 0; fn < 4; fn++)
          xw[mloc * 64 + fn * 16 + (lane & 15)] = acc[fm][fn][r];
      }
  }
  __syncthreads();
  if (!(wid & 1)) {
    unsigned short hv64[4][4][4];
#pragma unroll
    for (int fm = 0; fm < 4; fm++)
#pragma unroll
      for (int r = 0; r < 4; r++) {
        int mloc = fm * 16 + (lane >> 4) * 4 + r;
#pragma unroll
        for (int fn = 0; fn < 4; fn++) {
          float g = acc[fm][fn][r];
          float u = xw[mloc * 64 + fn * 16 + (lane & 15)];
          float hv = (g / (1.f + __expf(-g))) * u;
          hv64[fm][r][fn] = f2bf(hv);
        }
      }
    // pass 2: all xw reads done (wave-wide DS order) -> safe to clobber
    unsigned short* stg = (unsigned short*)smem + (wid >> 1) * 8192;
#pragma unroll
    for (int fm = 0; fm < 4; fm++)
#pragma unroll
      for (int r = 0; r < 4; r++) {
        int mloc = fm * 16 + (lane >> 4) * 4 + r;
#pragma unroll
        for (int fn = 0; fn < 4; fn++)
          stg[mloc * 64 + fn * 16 + (lane & 15)] = hv64[fm][r][fn];
      }
    int mbase = row0 + (wid >> 1) * 64;
#pragma unroll
    for (int it = 0; it < 8; it++) {
      int mloc = it * 8 + (lane >> 3);
      int cseg = (lane & 7) * 8;
      bf16x8 v = *(const bf16x8*)(stg + mloc * 64 + cseg);
      *(bf16x8*)(hbuf + (size_t)(mbase + mloc) * I_DIM + n0h + cseg) = v;
    }
  }
}

// ---------------- GEMM2: part[row] = h @ Wd (f16, un-gated) ----------------
__global__ __launch_bounds__(256) void gemm2_kernel(
    const unsigned short* __restrict__ hbuf, // [ROWS_CAP][I] bf16
    const unsigned short* __restrict__ wd,   // [E][H][I] bf16 (transposed)
    _Float16* __restrict__ part,             // [ROWS_CAP][H] f16
    const int* __restrict__ meta) {
  int m_t, n_t;
  remap_tile(blockIdx.x, NT2 * MAX_MT, NT2, m_t, n_t);
  if (m_t >= meta[32]) return;
  int e = meta[64 + m_t];
  int row0 = meta[256 + m_t];
  int n0 = n_t * 128;

  __shared__ alignas(16) char smem[65536];

  int tid = threadIdx.x, lane = tid & 63, wid = tid >> 6;
  const unsigned short* asrc[4];
  const unsigned short* bsrc[4];
  {
    const unsigned short* wb = wd + (size_t)e * (size_t)H_DIM * I_DIM;
#pragma unroll
    for (int i = 0; i < 4; i++) {
      int r = i * 32 + (tid >> 3);
      int ch = ((tid & 7) ^ (r & 7)) * 8;
      asrc[i] = hbuf + (size_t)(row0 + r) * I_DIM + ch;
      bsrc[i] = wb + (size_t)(n0 + r) * I_DIM + ch;
    }
  }
  f32x4 acc[4][4] = {};
  int mrow = (wid >> 1) * 64 + (lane & 15);
  int brow = (wid & 1) * 64 + (lane & 15);

  STAGE1(0, 0);
  __syncthreads();
  int cur = 0;
  for (int kt = 0; kt < I_DIM / BK; kt++) {
    if (kt + 1 < I_DIM / BK) STAGE1(cur ^ 1, (kt + 1) * BK);
    const unsigned short* sA = (const unsigned short*)(smem + cur * 32768);
    const unsigned short* sB = sA + 8192;
#pragma unroll
    for (int kk = 0; kk < 2; kk++) {
      int krd = ((kk * 4 + (lane >> 4)) ^ (lane & 7)) * 8;
      short8 af[4], bf[4];
#pragma unroll
      for (int f = 0; f < 4; f++) {
        af[f] = *(const short8*)(sA + (mrow + f * 16) * BK + krd);
        bf[f] = *(const short8*)(sB + (brow + f * 16) * BK + krd);
      }
#pragma unroll
      for (int fm = 0; fm < 4; fm++)
#pragma unroll
        for (int fn = 0; fn < 4; fn++)
          acc[fm][fn] = __builtin_amdgcn_mfma_f32_16x16x32_bf16(af[fm], bf[fn], acc[fm][fn], 0, 0, 0);
    }
    __syncthreads();
    cur ^= 1;
  }
  // epilogue: LDS-restage to f16, then b128 coalesced stores
  _Float16* stg = (_Float16*)(smem + wid * 8192);  // 8KB per wave
#pragma unroll
  for (int fm = 0; fm < 4; fm++)
#pragma unroll
    for (int r = 0; r < 4; r++) {
      int mloc = fm * 16 + (lane >> 4) * 4 + r;
#pragma unroll
      for (int fn = 0; fn < 4; fn++)
        stg[mloc * 64 + fn * 16 + (lane & 15)] = (_Float16)acc[fm][fn][r];
    }
  int m0 = (wid >> 1) * 64;
  int nbase = n0 + (wid & 1) * 64;
#pragma unroll
  for (int it = 0; it < 8; it++) {
    int mloc = it * 8 + (lane >> 3);
    int cseg = (lane & 7) * 8;
    h16x8 v = *(const h16x8*)(stg + mloc * 64 + cseg);
    *(h16x8*)(part + (size_t)(row0 + m0 + mloc) * H_DIM + nbase + cseg) = v;
  }
}

// ---------------- combine: out[t] = w0*part[r0] + w1*part[r1] --------------
__global__ __launch_bounds__(256) void combine_kernel(
    const _Float16* __restrict__ part, const int* __restrict__ tok2row,
    const float* __restrict__ topk_w, float* __restrict__ out) {
  int t = blockIdx.x;
  int c = threadIdx.x * 8;
  int r0 = tok2row[2 * t], r1 = tok2row[2 * t + 1];
  float w0 = topk_w[2 * t], w1 = topk_w[2 * t + 1];
  h16x8 p0 = *(const h16x8*)(part + (size_t)r0 * H_DIM + c);
  h16x8 p1 = *(const h16x8*)(part + (size_t)r1 * H_DIM + c);
  float* o = out + (size_t)t * H_DIM + c;
  f32x4 lo, hi;
#pragma unroll
  for (int j = 0; j < 4; j++) lo[j] = w0 * (float)p0[j] + w1 * (float)p1[j];
#pragma unroll
  for (int j = 0; j < 4; j++) hi[j] = w0 * (float)p0[4 + j] + w1 * (float)p1[4 + j];
  *(f32x4*)o = lo;
  *(f32x4*)(o + 4) = hi;
}

extern "C" void kernel_launch(void* const* d_in, const int* in_sizes, int n_in,
                              void* d_out, int out_size, void* d_ws, size_t ws_size,
                              hipStream_t stream) {
  const float* x   = (const float*)d_in[0];
  const float* rw  = (const float*)d_in[1];
  const float* wgu = (const float*)d_in[2];
  const float* wdn = (const float*)d_in[3];
  float* out = (float*)d_out;

  char* ws = (char*)d_ws;
  size_t off = 0;
  auto alloc = [&](size_t bytes) {
    void* p = ws + off;
    off += (bytes + 255) & ~(size_t)255;
    return p;
  };
  int* meta            = (int*)alloc(4096);
  int* topk_idx        = (int*)alloc((size_t)2 * T_TOK * 4);
  float* topk_w        = (float*)alloc((size_t)2 * T_TOK * 4);
  int* tok2row         = (int*)alloc((size_t)2 * T_TOK * 4);
  int* row_token       = (int*)alloc((size_t)ROWS_CAP * 4);
  unsigned short* xb    = (unsigned short*)alloc((size_t)T_TOK * H_DIM * 2);
  unsigned short* wgu_t = (unsigned short*)alloc((size_t)E_NUM * 2 * I_DIM * H_DIM * 2);
  unsigned short* wd_t  = (unsigned short*)alloc((size_t)E_NUM * H_DIM * I_DIM * 2);
  unsigned short* hbuf  = (unsigned short*)alloc((size_t)ROWS_CAP * I_DIM * 2);
  // part[ROWS_CAP][H] f16 (71.3 MB) aliases wgu_t (92.3 MB; dead after gemm1)
  _Float16* part = (_Float16*)wgu_t;

  if (off > ws_size) { // workspace too small: fail loudly (zero output)
    (void)hipMemsetAsync(d_out, 0, (size_t)out_size * sizeof(float), stream);
    return;
  }

  (void)hipMemsetAsync(meta, 0, 4096, stream);

  // conversions (x-convert fused into router)
  tcvt_kernel<<<dim3(2 * I_DIM / 64, H_DIM / 64, E_NUM), 256, 0, stream>>>(wgu, wgu_t, H_DIM, 2 * I_DIM);
  tcvt_kernel<<<dim3(H_DIM / 64, I_DIM / 64, E_NUM), 256, 0, stream>>>(wdn, wd_t, I_DIM, H_DIM);

  // routing
  router_kernel<<<T_TOK / 4, 256, 0, stream>>>(x, rw, xb, topk_idx, topk_w, meta);
  scan_kernel<<<1, 64, 0, stream>>>(meta, row_token);
  bucket_kernel<<<(2 * T_TOK + 255) / 256, 256, 0, stream>>>(topk_idx, meta, row_token, tok2row);

  // grouped expert MLP
  gemm1_kernel<<<NT1 * MAX_MT, 256, 0, stream>>>(xb, wgu_t, hbuf, row_token, meta);
  gemm2_kernel<<<NT2 * MAX_MT, 256, 0, stream>>>(hbuf, wd_t, part, meta);
  combine_kernel<<<T_TOK, 256, 0, stream>>>(part, tok2row, topk_w, out);
}

// Round 8
// 757.607 us; speedup vs baseline: 1.4959x; 1.0092x over previous
//
#include <hip/hip_runtime.h>
#include <hip/hip_bf16.h>
#include <cstdint>
#include <cstddef>

#define T_TOK 8192
#define H_DIM 2048
#define I_DIM 1408
#define E_NUM 8
#define BM 128
#define BK 64
#define ROWS_CAP (2 * T_TOK + E_NUM * BM) /* 17408 */
#define MAX_MT (ROWS_CAP / BM)            /* 136 */
#define NT1 (I_DIM / 64)                  /* 22 */
#define NT2 (H_DIM / 128)                 /* 16 */

typedef __attribute__((ext_vector_type(8))) short short8;
typedef __attribute__((ext_vector_type(4))) float f32x4;
typedef __attribute__((ext_vector_type(8))) unsigned short bf16x8;
typedef __attribute__((ext_vector_type(4))) unsigned short bf16x4;
typedef __attribute__((ext_vector_type(8))) _Float16 h16x8;

static __device__ __forceinline__ unsigned short f2bf(float f) {
  unsigned u = __float_as_uint(f);
  u += 0x7FFFu + ((u >> 16) & 1u);   // round-to-nearest-even
  return (unsigned short)(u >> 16);
}

static __device__ __forceinline__ void gld_lds16(const void* g, void* l) {
  __builtin_amdgcn_global_load_lds(
      (__attribute__((address_space(1))) unsigned int*)g,
      (__attribute__((address_space(3))) unsigned int*)l, 16, 0, 0);
}

// XCD-chunked bijective remap (nb % 8 == 0) + M-groups-of-4 intra order.
static __device__ __forceinline__ void remap_tile(int bid, int nb, int nt_cols,
                                                  int& m_t, int& n_t) {
  int chunk = nb >> 3;
  int wg = (bid & 7) * chunk + (bid >> 3);
  int grp = wg / (nt_cols * 4);
  int rem = wg % (nt_cols * 4);
  n_t = rem >> 2;
  m_t = grp * 4 + (rem & 3);
}

// ---------------- router (fused x->bf16 convert) ---------------------------
__global__ __launch_bounds__(256) void router_kernel(
    const float* __restrict__ x, const float* __restrict__ rw,
    unsigned short* __restrict__ xb,
    int* __restrict__ topk_idx, float* __restrict__ topk_w, int* __restrict__ meta) {
  int t = blockIdx.x * 4 + (threadIdx.x >> 6);
  int lane = threadIdx.x & 63;
  const float* xr = x + (size_t)t * H_DIM;
  unsigned short* xbr = xb + (size_t)t * H_DIM;
  float acc[E_NUM];
#pragma unroll
  for (int e = 0; e < E_NUM; e++) acc[e] = 0.f;
  for (int j = lane * 4; j < H_DIM; j += 256) {
    f32x4 v = *(const f32x4*)(xr + j);
    bf16x4 b;
#pragma unroll
    for (int u = 0; u < 4; u++) b[u] = f2bf(v[u]);
    *(bf16x4*)(xbr + j) = b;
#pragma unroll
    for (int e = 0; e < E_NUM; e++) {
      f32x4 w = *(const f32x4*)(rw + e * H_DIM + j);
      acc[e] += v[0] * w[0] + v[1] * w[1] + v[2] * w[2] + v[3] * w[3];
    }
  }
#pragma unroll
  for (int e = 0; e < E_NUM; e++) {
    float v = acc[e];
#pragma unroll
    for (int s = 32; s > 0; s >>= 1) v += __shfl_xor(v, s);
    acc[e] = v;
  }
  if (lane == 0) {
    int i0 = 0;
#pragma unroll
    for (int e = 1; e < E_NUM; e++) if (acc[e] > acc[i0]) i0 = e;
    int i1 = (i0 == 0) ? 1 : 0;
#pragma unroll
    for (int e = 0; e < E_NUM; e++) if (e != i0 && acc[e] > acc[i1]) i1 = e;
    float mx = acc[0];
#pragma unroll
    for (int e = 1; e < E_NUM; e++) mx = fmaxf(mx, acc[e]);
    float sum = 0.f, p[E_NUM];
#pragma unroll
    for (int e = 0; e < E_NUM; e++) { p[e] = expf(acc[e] - mx); sum += p[e]; }
    float inv = 1.f / sum;
    topk_idx[t * 2] = i0;  topk_idx[t * 2 + 1] = i1;
    topk_w[t * 2] = p[i0] * inv;  topk_w[t * 2 + 1] = p[i1] * inv;
    atomicAdd(&meta[i0], 1);
    atomicAdd(&meta[i1], 1);
  }
}

// ---------------- scan -----------------------------------------------------
__global__ void scan_kernel(int* __restrict__ meta, int* __restrict__ row_token) {
  __shared__ int s_off[E_NUM + 1];
  if (threadIdx.x == 0) {
    int o = 0, nt = 0;
    for (int e = 0; e < E_NUM; e++) {
      meta[16 + e] = o; s_off[e] = o;
      int c = meta[e];
      int mtc = (c + BM - 1) / BM;
      for (int m = 0; m < mtc; m++) { meta[64 + nt] = e; meta[256 + nt] = o + m * BM; nt++; }
      o += mtc * BM;
      meta[8 + e] = 0; // cursor
    }
    meta[16 + E_NUM] = o; s_off[E_NUM] = o;
    meta[32] = nt;
  }
  __syncthreads();
  for (int e = 0; e < E_NUM; e++) {
    int lo = s_off[e] + meta[e], hi = s_off[e + 1];
    for (int r = lo + (int)threadIdx.x; r < hi; r += 64) row_token[r] = -1;
  }
}

// ---------------- bucket ---------------------------------------------------
__global__ __launch_bounds__(256) void bucket_kernel(
    const int* __restrict__ topk_idx, int* __restrict__ meta,
    int* __restrict__ row_token, int* __restrict__ tok2row) {
  int i = blockIdx.x * 256 + threadIdx.x;
  if (i >= 2 * T_TOK) return;
  int e = topk_idx[i];
  int pos = atomicAdd(&meta[8 + e], 1);
  int r = meta[16 + e] + pos;
  row_token[r] = i >> 1;
  tok2row[i] = r;
}

// ---------------- transpose+convert (both weight tensors, one launch) ------
// [R][C] fp32 -> [C][R] bf16. f32x4 coalesced reads; row-major LDS store
// st[row][col] (writes ~2-way); transposed gather read st[rseg+k][c]
// (~4-way, 1.58x); bf16x8 coalesced global stores.
__global__ __launch_bounds__(256) void tcvt2_kernel(
    const float* __restrict__ wgu, const float* __restrict__ wdn,
    unsigned short* __restrict__ wgu_t, unsigned short* __restrict__ wd_t) {
  __shared__ unsigned short st[64][66];
  int z = blockIdx.z;
  const float* src; unsigned short* dst; int R, C;
  if (z < E_NUM) {
    R = H_DIM; C = 2 * I_DIM;
    src = wgu + (size_t)z * R * C;  dst = wgu_t + (size_t)z * R * C;
  } else {
    R = I_DIM; C = H_DIM;
    src = wdn + (size_t)(z - E_NUM) * R * C;  dst = wd_t + (size_t)(z - E_NUM) * R * C;
  }
  int c0 = blockIdx.x * 64, r0 = blockIdx.y * 64;
  if (c0 >= C || r0 >= R) return;
  int tid = threadIdx.x;
  int q = tid & 15, s = tid >> 4;   // q: col quad, s: 16 row slices
#pragma unroll
  for (int it = 0; it < 4; it++) {
    int rr = it * 16 + s;
    f32x4 v = *(const f32x4*)(src + (size_t)(r0 + rr) * C + c0 + q * 4);
#pragma unroll
    for (int j = 0; j < 4; j++) st[rr][q * 4 + j] = f2bf(v[j]);
  }
  __syncthreads();
  int cc = tid >> 3, rseg = (tid & 7) * 8;
#pragma unroll
  for (int it = 0; it < 2; it++) {
    int c = it * 32 + cc;
    bf16x8 v;
#pragma unroll
    for (int k = 0; k < 8; k++) v[k] = st[rseg + k][c];  // transposed read
    *(bf16x8*)(dst + (size_t)(c0 + c) * R + r0 + rseg) = v;
  }
}

// ---------------- GEMM1: h = silu(x@Wg)*(x@Wu), dbuf single-barrier --------
__global__ __launch_bounds__(256) void gemm1_kernel(
    const unsigned short* __restrict__ xb,   // [T][H] bf16
    const unsigned short* __restrict__ wgu,  // [E][2I][H] bf16 (transposed)
    unsigned short* __restrict__ hbuf,       // [ROWS_CAP][I] bf16
    const int* __restrict__ row_token, const int* __restrict__ meta) {
  int m_t, n_t;
  remap_tile(blockIdx.x, NT1 * MAX_MT, NT1, m_t, n_t);
  if (m_t >= meta[32]) return;
  int e = meta[64 + m_t];
  int row0 = meta[256 + m_t];
  int n0h = n_t * 64;

  __shared__ alignas(16) char smem[65536];  // 2 x (A 16K + B 16K)

  int tid = threadIdx.x, lane = tid & 63, wid = tid >> 6;
  const unsigned short* asrc[4];
  const unsigned short* bsrc[4];
  {
    const unsigned short* wb = wgu + (size_t)e * (2 * (size_t)I_DIM) * H_DIM;
#pragma unroll
    for (int i = 0; i < 4; i++) {
      int r = i * 32 + (tid >> 3);
      int ch = ((tid & 7) ^ (r & 7)) * 8;  // inverse-swizzled source chunk
      int tok = row_token[row0 + r];
      if (tok < 0) tok = 0;
      asrc[i] = xb + (size_t)tok * H_DIM + ch;
      int wr = (r < 64) ? (n0h + r) : (I_DIM + n0h + (r - 64));
      bsrc[i] = wb + (size_t)wr * H_DIM + ch;
    }
  }
  f32x4 acc[4][4] = {};
  int mrow = (wid >> 1) * 64 + (lane & 15);
  int brow = (wid & 1) * 64 + (lane & 15);

#define STAGE1(buf, kof_)                                                     \
  {                                                                           \
    int kof = (kof_);                                                         \
    char* b = smem + (buf) * 32768;                                           \
    _Pragma("unroll") for (int i = 0; i < 4; i++) {                           \
      gld_lds16(asrc[i] + kof, b + i * 4096 + wid * 1024);                    \
      gld_lds16(bsrc[i] + kof, b + 16384 + i * 4096 + wid * 1024);            \
    }                                                                         \
  }

  STAGE1(0, 0);
  __syncthreads();
  int cur = 0;
  for (int kt = 0; kt < H_DIM / BK; kt++) {
    if (kt + 1 < H_DIM / BK) STAGE1(cur ^ 1, (kt + 1) * BK);
    const unsigned short* sA = (const unsigned short*)(smem + cur * 32768);
    const unsigned short* sB = sA + 8192;
#pragma unroll
    for (int kk = 0; kk < 2; kk++) {
      int krd = ((kk * 4 + (lane >> 4)) ^ (lane & 7)) * 8;
      short8 af[4], bf[4];
#pragma unroll
      for (int f = 0; f < 4; f++) {
        af[f] = *(const short8*)(sA + (mrow + f * 16) * BK + krd);
        bf[f] = *(const short8*)(sB + (brow + f * 16) * BK + krd);
      }
#pragma unroll
      for (int fm = 0; fm < 4; fm++)
#pragma unroll
        for (int fn = 0; fn < 4; fn++)
          acc[fm][fn] = __builtin_amdgcn_mfma_f32_16x16x32_bf16(af[fm], bf[fn], acc[fm][fn], 0, 0, 0);
    }
    __syncthreads();
    cur ^= 1;
  }

  // SwiGLU epilogue: odd waves (U) publish via LDS, even waves combine.
  float* xw = (float*)smem + (wid >> 1) * 4096;  // 64x64 f32 per wave-pair
  if (wid & 1) {
#pragma unroll
    for (int fm = 0; fm < 4; fm++)
#pragma unroll
      for (int r = 0; r < 4; r++) {
        int mloc = fm * 16 + (lane >> 4) * 4 + r;
#pragma unroll
        for (int fn = 0; fn < 4; fn++)
          xw[mloc * 64 + fn * 16 + (lane & 15)] = acc[fm][fn][r];
      }
  }
  __syncthreads();
  if (!(wid & 1)) {
    int mbase = row0 + (wid >> 1) * 64;
#pragma unroll
    for (int fm = 0; fm < 4; fm++)
#pragma unroll
      for (int r = 0; r < 4; r++) {
        int mloc = fm * 16 + (lane >> 4) * 4 + r;
        size_t rbase = (size_t)(mbase + mloc) * I_DIM + n0h;
#pragma unroll
        for (int fn = 0; fn < 4; fn++) {
          float g = acc[fm][fn][r];
          float u = xw[mloc * 64 + fn * 16 + (lane & 15)];
          float hv = (g / (1.f + __expf(-g))) * u;
          hbuf[rbase + fn * 16 + (lane & 15)] = f2bf(hv);
        }
      }
  }
}

// ---------------- GEMM2: part[row] = h @ Wd (f16, un-gated) ----------------
__global__ __launch_bounds__(256) void gemm2_kernel(
    const unsigned short* __restrict__ hbuf, // [ROWS_CAP][I] bf16
    const unsigned short* __restrict__ wd,   // [E][H][I] bf16 (transposed)
    _Float16* __restrict__ part,             // [ROWS_CAP][H] f16
    const int* __restrict__ meta) {
  int m_t, n_t;
  remap_tile(blockIdx.x, NT2 * MAX_MT, NT2, m_t, n_t);
  if (m_t >= meta[32]) return;
  int e = meta[64 + m_t];
  int row0 = meta[256 + m_t];
  int n0 = n_t * 128;

  __shared__ alignas(16) char smem[65536];

  int tid = threadIdx.x, lane = tid & 63, wid = tid >> 6;
  const unsigned short* asrc[4];
  const unsigned short* bsrc[4];
  {
    const unsigned short* wb = wd + (size_t)e * (size_t)H_DIM * I_DIM;
#pragma unroll
    for (int i = 0; i < 4; i++) {
      int r = i * 32 + (tid >> 3);
      int ch = ((tid & 7) ^ (r & 7)) * 8;
      asrc[i] = hbuf + (size_t)(row0 + r) * I_DIM + ch;
      bsrc[i] = wb + (size_t)(n0 + r) * I_DIM + ch;
    }
  }
  f32x4 acc[4][4] = {};
  int mrow = (wid >> 1) * 64 + (lane & 15);
  int brow = (wid & 1) * 64 + (lane & 15);

  STAGE1(0, 0);
  __syncthreads();
  int cur = 0;
  for (int kt = 0; kt < I_DIM / BK; kt++) {
    if (kt + 1 < I_DIM / BK) STAGE1(cur ^ 1, (kt + 1) * BK);
    const unsigned short* sA = (const unsigned short*)(smem + cur * 32768);
    const unsigned short* sB = sA + 8192;
#pragma unroll
    for (int kk = 0; kk < 2; kk++) {
      int krd = ((kk * 4 + (lane >> 4)) ^ (lane & 7)) * 8;
      short8 af[4], bf[4];
#pragma unroll
      for (int f = 0; f < 4; f++) {
        af[f] = *(const short8*)(sA + (mrow + f * 16) * BK + krd);
        bf[f] = *(const short8*)(sB + (brow + f * 16) * BK + krd);
      }
#pragma unroll
      for (int fm = 0; fm < 4; fm++)
#pragma unroll
        for (int fn = 0; fn < 4; fn++)
          acc[fm][fn] = __builtin_amdgcn_mfma_f32_16x16x32_bf16(af[fm], bf[fn], acc[fm][fn], 0, 0, 0);
    }
    __syncthreads();
    cur ^= 1;
  }
  // epilogue: direct f16 stores (no atomics, no gather)
  int m0 = (wid >> 1) * 64;
  int nn0 = n0 + (wid & 1) * 64 + (lane & 15);
#pragma unroll
  for (int fm = 0; fm < 4; fm++)
#pragma unroll
    for (int r = 0; r < 4; r++) {
      int rr = row0 + m0 + fm * 16 + (lane >> 4) * 4 + r;
      _Float16* prow = part + (size_t)rr * H_DIM + nn0;
#pragma unroll
      for (int fn = 0; fn < 4; fn++)
        prow[fn * 16] = (_Float16)acc[fm][fn][r];
    }
}

// ---------------- combine: out[t] = w0*part[r0] + w1*part[r1] --------------
__global__ __launch_bounds__(256) void combine_kernel(
    const _Float16* __restrict__ part, const int* __restrict__ tok2row,
    const float* __restrict__ topk_w, float* __restrict__ out) {
  int t = blockIdx.x;
  int c = threadIdx.x * 8;
  int r0 = tok2row[2 * t], r1 = tok2row[2 * t + 1];
  float w0 = topk_w[2 * t], w1 = topk_w[2 * t + 1];
  h16x8 p0 = *(const h16x8*)(part + (size_t)r0 * H_DIM + c);
  h16x8 p1 = *(const h16x8*)(part + (size_t)r1 * H_DIM + c);
  float* o = out + (size_t)t * H_DIM + c;
  f32x4 lo, hi;
#pragma unroll
  for (int j = 0; j < 4; j++) lo[j] = w0 * (float)p0[j] + w1 * (float)p1[j];
#pragma unroll
  for (int j = 0; j < 4; j++) hi[j] = w0 * (float)p0[4 + j] + w1 * (float)p1[4 + j];
  *(f32x4*)o = lo;
  *(f32x4*)(o + 4) = hi;
}

extern "C" void kernel_launch(void* const* d_in, const int* in_sizes, int n_in,
                              void* d_out, int out_size, void* d_ws, size_t ws_size,
                              hipStream_t stream) {
  const float* x   = (const float*)d_in[0];
  const float* rw  = (const float*)d_in[1];
  const float* wgu = (const float*)d_in[2];
  const float* wdn = (const float*)d_in[3];
  float* out = (float*)d_out;

  char* ws = (char*)d_ws;
  size_t off = 0;
  auto alloc = [&](size_t bytes) {
    void* p = ws + off;
    off += (bytes + 255) & ~(size_t)255;
    return p;
  };
  int* meta            = (int*)alloc(4096);
  int* topk_idx        = (int*)alloc((size_t)2 * T_TOK * 4);
  float* topk_w        = (float*)alloc((size_t)2 * T_TOK * 4);
  int* tok2row         = (int*)alloc((size_t)2 * T_TOK * 4);
  int* row_token       = (int*)alloc((size_t)ROWS_CAP * 4);
  unsigned short* xb    = (unsigned short*)alloc((size_t)T_TOK * H_DIM * 2);
  unsigned short* wgu_t = (unsigned short*)alloc((size_t)E_NUM * 2 * I_DIM * H_DIM * 2);
  unsigned short* wd_t  = (unsigned short*)alloc((size_t)E_NUM * H_DIM * I_DIM * 2);
  unsigned short* hbuf  = (unsigned short*)alloc((size_t)ROWS_CAP * I_DIM * 2);
  // part[ROWS_CAP][H] f16 (71.3 MB) aliases wgu_t (92.3 MB; dead after gemm1)
  _Float16* part = (_Float16*)wgu_t;

  if (off > ws_size) { // workspace too small: fail loudly (zero output)
    (void)hipMemsetAsync(d_out, 0, (size_t)out_size * sizeof(float), stream);
    return;
  }

  (void)hipMemsetAsync(meta, 0, 4096, stream);

  // weight conversions (both tensors, one launch); x-convert fused in router
  tcvt2_kernel<<<dim3(2 * I_DIM / 64, H_DIM / 64, 2 * E_NUM), 256, 0, stream>>>(wgu, wdn, wgu_t, wd_t);

  // routing
  router_kernel<<<T_TOK / 4, 256, 0, stream>>>(x, rw, xb, topk_idx, topk_w, meta);
  scan_kernel<<<1, 64, 0, stream>>>(meta, row_token);
  bucket_kernel<<<(2 * T_TOK + 255) / 256, 256, 0, stream>>>(topk_idx, meta, row_token, tok2row);

  // grouped expert MLP
  gemm1_kernel<<<NT1 * MAX_MT, 256, 0, stream>>>(xb, wgu_t, hbuf, row_token, meta);
  gemm2_kernel<<<NT2 * MAX_MT, 256, 0, stream>>>(hbuf, wd_t, part, meta);
  combine_kernel<<<T_TOK, 256, 0, stream>>>(part, tok2row, topk_w, out);
}